// Round 1
// baseline (591.085 us; speedup 1.0000x reference)
//
#include <hip/hip_runtime.h>
#include <cmath>

// ---- problem constants ----
#define BATCH 16
#define HEADS 16
#define SEQ   512
#define DIM   64
#define QT    32          // q rows per block
#define NCHUNK 8          // key chunks of 64

#define LAMBDA_A 0.33f
#define LAMBDA_D 0.33f
#define LAMBDA_J 0.34f    // 1 - 0.33 - 0.33
#define NEG_BIG  1.0e12f

typedef float  floatx4 __attribute__((ext_vector_type(4)));
typedef short  shortx8 __attribute__((ext_vector_type(8)));
typedef short  shortx4 __attribute__((ext_vector_type(4)));

__device__ __forceinline__ unsigned short f2bf(float x){
  unsigned u = __builtin_bit_cast(unsigned, x);
  u += 0x7FFFu + ((u >> 16) & 1u);          // round-to-nearest-even
  return (unsigned short)(u >> 16);
}

// ---------------- per-(b,q) row stats: inv_adj_sum, max(-dist), 1/sum(exp) ----------------
__global__ __launch_bounds__(64) void stats_kernel(const float* __restrict__ mask,
                                                   const float* __restrict__ adj,
                                                   const float* __restrict__ dist,
                                                   float* __restrict__ ws){
  int bid  = blockIdx.x;              // b*512 + q
  int b    = bid >> 9;
  int lane = threadIdx.x;
  const float* arow = adj  + (size_t)bid * SEQ;
  const float* drow = dist + (size_t)bid * SEQ;
  const float* mrow = mask + b * SEQ;

  float asum = 0.f, dmax = -INFINITY;
  float xs[8];
#pragma unroll
  for (int i = 0; i < 8; i++){
    int n = lane + i * 64;
    asum += arow[n];
    float mk = mrow[n];
    float x  = (mk == 0.f) ? -INFINITY : -drow[n];
    xs[i] = x;
    dmax  = fmaxf(dmax, x);
  }
#pragma unroll
  for (int off = 1; off < 64; off <<= 1){
    asum += __shfl_xor(asum, off);
    dmax  = fmaxf(dmax, __shfl_xor(dmax, off));
  }
  float lsum = 0.f;
#pragma unroll
  for (int i = 0; i < 8; i++) lsum += __expf(xs[i] - dmax);
#pragma unroll
  for (int off = 1; off < 64; off <<= 1) lsum += __shfl_xor(lsum, off);

  if (lane == 0){
    ws[bid]             = 1.f / (asum + 1e-6f);
    ws[8192  + bid]     = dmax;
    ws[16384 + bid]     = 1.f / lsum;
  }
}

// ---------------- fused attention ----------------
__global__ __launch_bounds__(256, 3) void attn_kernel(
    const float* __restrict__ Q, const float* __restrict__ K, const float* __restrict__ V,
    const float* __restrict__ mask, const float* __restrict__ adj, const float* __restrict__ dist,
    const float* __restrict__ ws, float* __restrict__ out, float* __restrict__ pattn){

  int bx  = blockIdx.x;
  int qt  = bx & 15;
  int bh  = bx >> 4;
  int b   = bh >> 4;
  int q0  = qt * QT;

  int tid  = threadIdx.x;
  int wave = tid >> 6;
  int lane = tid & 63;
  int l15  = lane & 15;
  int quad = lane >> 4;

  __shared__ short sQ [32 * 72];        // bf16 Q tile (prescaled by 1/8), stride 72
  __shared__ short sKV[64 * 72];        // bf16 K chunk / V^T chunk, stride 72
  __shared__ short sPW[32 * 520];       // bf16 p_weighted, stride 520
  __shared__ float sMask[SEQ];
  __shared__ float sRedM[2][32];
  __shared__ float sRedS[2][32];

  const float* Qb = Q + ((size_t)bh * SEQ + q0) * DIM;
  const float* Kb = K + (size_t)bh * SEQ * DIM;
  const float* Vb = V + (size_t)bh * SEQ * DIM;

  // ---- stage Q (scaled) + mask ----
#pragma unroll
  for (int i = 0; i < 2; i++){
    int f = i * 1024 + tid * 4;
    floatx4 v = *(const floatx4*)(Qb + f);
    int row = f >> 6, col = f & 63;
    shortx4 h;
    h[0] = (short)f2bf(v[0] * 0.125f);
    h[1] = (short)f2bf(v[1] * 0.125f);
    h[2] = (short)f2bf(v[2] * 0.125f);
    h[3] = (short)f2bf(v[3] * 0.125f);
    *(shortx4*)&sQ[row * 72 + col] = h;
  }
  sMask[tid]       = mask[b * SEQ + tid];
  sMask[tid + 256] = mask[b * SEQ + tid + 256];

  int mtile = wave & 1;     // which 16-row half of the q tile
  int p     = wave >> 1;    // ntile parity

  floatx4 acc[16];
#pragma unroll
  for (int j = 0; j < 16; j++) acc[j] = (floatx4)0.f;

  // ---- QK^T over 8 chunks of 64 keys ----
  for (int c = 0; c < NCHUNK; c++){
    if (c) __syncthreads();
    const float* Kc = Kb + c * 64 * DIM;
#pragma unroll
    for (int i = 0; i < 4; i++){
      int f = i * 1024 + tid * 4;
      floatx4 v = *(const floatx4*)(Kc + f);
      int row = f >> 6, col = f & 63;
      shortx4 h;
      h[0] = (short)f2bf(v[0]);
      h[1] = (short)f2bf(v[1]);
      h[2] = (short)f2bf(v[2]);
      h[3] = (short)f2bf(v[3]);
      *(shortx4*)&sKV[row * 72 + col] = h;
    }
    __syncthreads();
#pragma unroll
    for (int ks = 0; ks < 2; ks++){
      shortx8 af = *(const shortx8*)&sQ[(mtile * 16 + l15) * 72 + ks * 32 + quad * 8];
      shortx8 b0 = *(const shortx8*)&sKV[(p * 16 + l15) * 72 + ks * 32 + quad * 8];
      acc[2 * c] = __builtin_amdgcn_mfma_f32_16x16x32_bf16(af, b0, acc[2 * c], 0, 0, 0);
      shortx8 b1 = *(const shortx8*)&sKV[((p + 2) * 16 + l15) * 72 + ks * 32 + quad * 8];
      acc[2 * c + 1] = __builtin_amdgcn_mfma_f32_16x16x32_bf16(af, b1, acc[2 * c + 1], 0, 0, 0);
    }
  }

  // ---- softmax (rows live in quad: row = mtile*16 + quad*4 + r, col = (2j+p)*16 + l15) ----
  float vmax[4] = {-INFINITY, -INFINITY, -INFINITY, -INFINITY};
#pragma unroll
  for (int j = 0; j < 16; j++){
    int n = (2 * j + p) * 16 + l15;
    bool msk0 = (sMask[n] == 0.f);
#pragma unroll
    for (int r = 0; r < 4; r++){
      float s = msk0 ? -NEG_BIG : acc[j][r];
      acc[j][r] = s;
      vmax[r] = fmaxf(vmax[r], s);
    }
  }
#pragma unroll
  for (int r = 0; r < 4; r++){
#pragma unroll
    for (int off = 1; off < 16; off <<= 1)
      vmax[r] = fmaxf(vmax[r], __shfl_xor(vmax[r], off));
  }
  if (l15 == 0){
#pragma unroll
    for (int r = 0; r < 4; r++) sRedM[p][mtile * 16 + quad * 4 + r] = vmax[r];
  }
  __syncthreads();
  float mrow[4];
#pragma unroll
  for (int r = 0; r < 4; r++){
    int ridx = mtile * 16 + quad * 4 + r;
    mrow[r] = fmaxf(sRedM[0][ridx], sRedM[1][ridx]);
  }
  float vsum[4] = {0.f, 0.f, 0.f, 0.f};
#pragma unroll
  for (int j = 0; j < 16; j++){
#pragma unroll
    for (int r = 0; r < 4; r++){
      float e = __expf(acc[j][r] - mrow[r]);
      acc[j][r] = e;
      vsum[r] += e;
    }
  }
#pragma unroll
  for (int r = 0; r < 4; r++){
#pragma unroll
    for (int off = 1; off < 16; off <<= 1)
      vsum[r] += __shfl_xor(vsum[r], off);
  }
  if (l15 == 0){
#pragma unroll
    for (int r = 0; r < 4; r++) sRedS[p][mtile * 16 + quad * 4 + r] = vsum[r];
  }
  __syncthreads();
  float inv_l[4];
#pragma unroll
  for (int r = 0; r < 4; r++){
    int ridx = mtile * 16 + quad * 4 + r;
    inv_l[r] = 1.f / (sRedS[0][ridx] + sRedS[1][ridx]);
  }

  // ---- p_attn store + p_weighted build ----
  float* pA = pattn + ((size_t)bh * SEQ + q0) * SEQ;
  const float* arow_base = adj  + ((size_t)b * SEQ + q0) * SEQ;
  const float* drow_base = dist + ((size_t)b * SEQ + q0) * SEQ;
  const float* iadj = ws;
  const float* mds  = ws + 8192;
  const float* ils  = ws + 16384;

#pragma unroll
  for (int r = 0; r < 4; r++){
    int rl = mtile * 16 + quad * 4 + r;          // local q row
    int qg = b * SEQ + q0 + rl;
    float ia = iadj[qg];
    float md = mds[qg];
    float il = ils[qg];
#pragma unroll
    for (int j = 0; j < 16; j++){
      int n = (2 * j + p) * 16 + l15;
      float pa = acc[j][r] * inv_l[r];
      __builtin_nontemporal_store(pa, &pA[(size_t)rl * SEQ + n]);
      float a  = arow_base[(size_t)rl * SEQ + n];
      float dd = drow_base[(size_t)rl * SEQ + n];
      float mk = sMask[n];
      float pd = (mk == 0.f) ? 0.f : __expf(-dd - md) * il;
      float pw = LAMBDA_A * pa + LAMBDA_D * pd + LAMBDA_J * a * ia;
      sPW[rl * 520 + n] = (short)f2bf(pw);
    }
  }
  __syncthreads();

  // ---- PV: out = PW(32x512) @ V(512x64), V transposed chunk-wise through LDS ----
  floatx4 acc2[2];
  acc2[0] = (floatx4)0.f;
  acc2[1] = (floatx4)0.f;
  int mtile2 = wave & 1;
  int p2     = wave >> 1;

  for (int c = 0; c < NCHUNK; c++){
    if (c) __syncthreads();
    {
      int n = tid & 63, g = tid >> 6;
      const float* Vc = Vb + c * 64 * DIM;
      shortx8 w0, w1;
#pragma unroll
      for (int i = 0; i < 8; i++)  w0[i] = (short)f2bf(Vc[(g * 16 + i) * DIM + n]);
#pragma unroll
      for (int i = 0; i < 8; i++)  w1[i] = (short)f2bf(Vc[(g * 16 + 8 + i) * DIM + n]);
      *(shortx8*)&sKV[n * 72 + g * 16]     = w0;
      *(shortx8*)&sKV[n * 72 + g * 16 + 8] = w1;
    }
    __syncthreads();
#pragma unroll
    for (int ks = 0; ks < 2; ks++){
      shortx8 af = *(const shortx8*)&sPW[(mtile2 * 16 + l15) * 520 + c * 64 + ks * 32 + quad * 8];
      shortx8 b0 = *(const shortx8*)&sKV[(p2 * 16 + l15) * 72 + ks * 32 + quad * 8];
      acc2[0] = __builtin_amdgcn_mfma_f32_16x16x32_bf16(af, b0, acc2[0], 0, 0, 0);
      shortx8 b1 = *(const shortx8*)&sKV[((p2 + 2) * 16 + l15) * 72 + ks * 32 + quad * 8];
      acc2[1] = __builtin_amdgcn_mfma_f32_16x16x32_bf16(af, b1, acc2[1], 0, 0, 0);
    }
  }

  // ---- epilogue: out (B,H,S,D) ----
  float* ob = out + ((size_t)bh * SEQ + q0) * DIM;
#pragma unroll
  for (int t = 0; t < 2; t++){
    int nt = p2 + 2 * t;
#pragma unroll
    for (int r = 0; r < 4; r++){
      int rl = mtile2 * 16 + quad * 4 + r;
      __builtin_nontemporal_store(acc2[t][r], &ob[(size_t)rl * DIM + nt * 16 + l15]);
    }
  }
}

extern "C" void kernel_launch(void* const* d_in, const int* in_sizes, int n_in,
                              void* d_out, int out_size, void* d_ws, size_t ws_size,
                              hipStream_t stream){
  const float* Q    = (const float*)d_in[0];
  const float* K    = (const float*)d_in[1];
  const float* V    = (const float*)d_in[2];
  const float* mask = (const float*)d_in[3];
  const float* adj  = (const float*)d_in[4];
  const float* dist = (const float*)d_in[5];
  float* out   = (float*)d_out;
  float* pattn = out + (size_t)BATCH * HEADS * SEQ * DIM;   // 8,388,608
  float* ws    = (float*)d_ws;

  stats_kernel<<<BATCH * SEQ, 64, 0, stream>>>(mask, adj, dist, ws);
  attn_kernel<<<BATCH * HEADS * (SEQ / QT), 256, 0, stream>>>(Q, K, V, mask, adj, dist,
                                                              ws, out, pattn);
}

// Round 2
// 565.232 us; speedup vs baseline: 1.0457x; 1.0457x over previous
//
#include <hip/hip_runtime.h>
#include <cmath>

// ---- problem constants ----
#define BATCH 16
#define HEADS 16
#define SEQ   512
#define DIM   64
#define QT    32          // q rows per block
#define NCHUNK 8          // key chunks of 64

#define LAMBDA_A 0.33f
#define LAMBDA_D 0.33f
#define LAMBDA_J 0.34f    // 1 - 0.33 - 0.33
#define NEG_BIG  1.0e12f

typedef float  floatx4 __attribute__((ext_vector_type(4)));
typedef short  shortx8 __attribute__((ext_vector_type(8)));
typedef short  shortx4 __attribute__((ext_vector_type(4)));

__device__ __forceinline__ unsigned short f2bf(float x){
  unsigned u = __builtin_bit_cast(unsigned, x);
  u += 0x7FFFu + ((u >> 16) & 1u);          // round-to-nearest-even
  return (unsigned short)(u >> 16);
}

// One fused kernel: per-block = one (b, h, q-tile of 32 rows).
// Grid order: h innermost so the 16 blocks sharing (b,qt) adj/dist rows are
// co-resident (L2/LLC reuse); qt next so same-head blocks also co-resident.
__global__ __launch_bounds__(256, 4) void attn_kernel(
    const float* __restrict__ Q, const float* __restrict__ K, const float* __restrict__ V,
    const float* __restrict__ mask, const float* __restrict__ adj, const float* __restrict__ dist,
    float* __restrict__ out, float* __restrict__ pattn){

  int bx  = blockIdx.x;
  int h   = bx & 15;
  int rest= bx >> 4;
  int qt  = rest & 15;
  int b   = rest >> 4;
  int bh  = b * HEADS + h;
  int q0  = qt * QT;

  int tid  = threadIdx.x;
  int wave = tid >> 6;
  int lane = tid & 63;
  int l15  = lane & 15;
  int quad = lane >> 4;

  __shared__ short sQ [32 * 72];        // bf16 Q tile (prescaled by 1/8)
  __shared__ short sKV[64 * 72];        // bf16 K chunk / V^T chunk
  __shared__ short sPW[32 * 72];        // bf16 p_weighted, one 64-col chunk
  __shared__ float sMask[SEQ];
  __shared__ float sRedM[2][32];
  __shared__ float sRedS[2][32];
  __shared__ float sRowA[32];           // 1/(sum(adj)+eps) per local q row
  __shared__ float sRowD[32];           // 1/sum(exp(-dist)) per local q row

  const float* Qb = Q + ((size_t)bh * SEQ + q0) * DIM;
  const float* Kb = K + (size_t)bh * SEQ * DIM;
  const float* Vb = V + (size_t)bh * SEQ * DIM;

  // ---- stage Q (scaled) + mask ----
#pragma unroll
  for (int i = 0; i < 2; i++){
    int f = i * 1024 + tid * 4;
    floatx4 v = *(const floatx4*)(Qb + f);
    int row = f >> 6, col = f & 63;
    shortx4 hh;
    hh[0] = (short)f2bf(v[0] * 0.125f);
    hh[1] = (short)f2bf(v[1] * 0.125f);
    hh[2] = (short)f2bf(v[2] * 0.125f);
    hh[3] = (short)f2bf(v[3] * 0.125f);
    *(shortx4*)&sQ[row * 72 + col] = hh;
  }
  sMask[tid]       = mask[b * SEQ + tid];
  sMask[tid + 256] = mask[b * SEQ + tid + 256];
  __syncthreads();

  // ---- fused row stats: adj row sum, dist exp-sum (no max needed: dist in [0,1)) ----
  {
    int rl  = tid >> 3;        // 0..31 local q row, 8 threads per row
    int sub = tid & 7;
    const float* arow = adj  + ((size_t)b * SEQ + q0 + rl) * SEQ;
    const float* drow = dist + ((size_t)b * SEQ + q0 + rl) * SEQ;
    float asum = 0.f, dsum = 0.f;
#pragma unroll
    for (int k = 0; k < 16; k++){
      int c4 = (k * 8 + sub) * 4;
      floatx4 a4 = *(const floatx4*)(arow + c4);
      floatx4 d4 = *(const floatx4*)(drow + c4);
      asum += (a4[0] + a4[1]) + (a4[2] + a4[3]);
#pragma unroll
      for (int i = 0; i < 4; i++){
        float mk = sMask[c4 + i];
        dsum += (mk == 0.f) ? 0.f : __expf(-d4[i]);
      }
    }
#pragma unroll
    for (int off = 1; off < 8; off <<= 1){
      asum += __shfl_xor(asum, off);
      dsum += __shfl_xor(dsum, off);
    }
    if (sub == 0){
      sRowA[rl] = 1.f / (asum + 1e-6f);
      sRowD[rl] = 1.f / dsum;
    }
  }

  int mtile = wave & 1;     // which 16-row half of the q tile
  int p     = wave >> 1;    // ntile parity

  floatx4 acc[16];
#pragma unroll
  for (int j = 0; j < 16; j++) acc[j] = (floatx4)0.f;

  // ---- QK^T over 8 chunks of 64 keys ----
  for (int c = 0; c < NCHUNK; c++){
    if (c) __syncthreads();
    const float* Kc = Kb + c * 64 * DIM;
#pragma unroll
    for (int i = 0; i < 4; i++){
      int f = i * 1024 + tid * 4;
      floatx4 v = *(const floatx4*)(Kc + f);
      int row = f >> 6, col = f & 63;
      shortx4 hh;
      hh[0] = (short)f2bf(v[0]);
      hh[1] = (short)f2bf(v[1]);
      hh[2] = (short)f2bf(v[2]);
      hh[3] = (short)f2bf(v[3]);
      *(shortx4*)&sKV[row * 72 + col] = hh;
    }
    __syncthreads();
#pragma unroll
    for (int ks = 0; ks < 2; ks++){
      shortx8 af = *(const shortx8*)&sQ[(mtile * 16 + l15) * 72 + ks * 32 + quad * 8];
      shortx8 b0 = *(const shortx8*)&sKV[(p * 16 + l15) * 72 + ks * 32 + quad * 8];
      acc[2 * c] = __builtin_amdgcn_mfma_f32_16x16x32_bf16(af, b0, acc[2 * c], 0, 0, 0);
      shortx8 b1 = *(const shortx8*)&sKV[((p + 2) * 16 + l15) * 72 + ks * 32 + quad * 8];
      acc[2 * c + 1] = __builtin_amdgcn_mfma_f32_16x16x32_bf16(af, b1, acc[2 * c + 1], 0, 0, 0);
    }
  }

  // ---- softmax (row = mtile*16 + quad*4 + r, col = (2j+p)*16 + l15) ----
  float vmax[4] = {-INFINITY, -INFINITY, -INFINITY, -INFINITY};
#pragma unroll
  for (int j = 0; j < 16; j++){
    int n = (2 * j + p) * 16 + l15;
    bool msk0 = (sMask[n] == 0.f);
#pragma unroll
    for (int r = 0; r < 4; r++){
      float s = msk0 ? -NEG_BIG : acc[j][r];
      acc[j][r] = s;
      vmax[r] = fmaxf(vmax[r], s);
    }
  }
#pragma unroll
  for (int r = 0; r < 4; r++){
#pragma unroll
    for (int off = 1; off < 16; off <<= 1)
      vmax[r] = fmaxf(vmax[r], __shfl_xor(vmax[r], off));
  }
  if (l15 == 0){
#pragma unroll
    for (int r = 0; r < 4; r++) sRedM[p][mtile * 16 + quad * 4 + r] = vmax[r];
  }
  __syncthreads();
  float mrow[4];
#pragma unroll
  for (int r = 0; r < 4; r++){
    int ridx = mtile * 16 + quad * 4 + r;
    mrow[r] = fmaxf(sRedM[0][ridx], sRedM[1][ridx]);
  }
  float vsum[4] = {0.f, 0.f, 0.f, 0.f};
#pragma unroll
  for (int j = 0; j < 16; j++){
#pragma unroll
    for (int r = 0; r < 4; r++){
      float e = __expf(acc[j][r] - mrow[r]);
      acc[j][r] = e;
      vsum[r] += e;
    }
  }
#pragma unroll
  for (int r = 0; r < 4; r++){
#pragma unroll
    for (int off = 1; off < 16; off <<= 1)
      vsum[r] += __shfl_xor(vsum[r], off);
  }
  if (l15 == 0){
#pragma unroll
    for (int r = 0; r < 4; r++) sRedS[p][mtile * 16 + quad * 4 + r] = vsum[r];
  }
  __syncthreads();
  float inv_l[4];
#pragma unroll
  for (int r = 0; r < 4; r++){
    int ridx = mtile * 16 + quad * 4 + r;
    inv_l[r] = 1.f / (sRedS[0][ridx] + sRedS[1][ridx]);
  }

  // ---- fused epilogue: per 64-key chunk, build p_weighted tile + stage V^T, PV MFMA ----
  float* pA = pattn + ((size_t)bh * SEQ + q0) * SEQ;
  const float* arow_base = adj  + ((size_t)b * SEQ + q0) * SEQ;
  const float* drow_base = dist + ((size_t)b * SEQ + q0) * SEQ;

  floatx4 acc2[2];
  acc2[0] = (floatx4)0.f;
  acc2[1] = (floatx4)0.f;

  for (int c = 0; c < NCHUNK; c++){
    if (c) __syncthreads();
    // stage V chunk transposed (V^T: [n=out-dim][k=key]) as bf16
    {
      int n = tid & 63, g = tid >> 6;
      const float* Vc = Vb + c * 64 * DIM;
      shortx8 w0, w1;
#pragma unroll
      for (int i = 0; i < 8; i++)  w0[i] = (short)f2bf(Vc[(g * 16 + i) * DIM + n]);
#pragma unroll
      for (int i = 0; i < 8; i++)  w1[i] = (short)f2bf(Vc[(g * 16 + 8 + i) * DIM + n]);
      *(shortx8*)&sKV[n * 72 + g * 16]     = w0;
      *(shortx8*)&sKV[n * 72 + g * 16 + 8] = w1;
    }
    // build p_weighted tile for this chunk + store p_attn
#pragma unroll
    for (int r = 0; r < 4; r++){
      int rl = mtile * 16 + quad * 4 + r;
      float ia = sRowA[rl];
      float il = sRowD[rl];
#pragma unroll
      for (int jj = 0; jj < 2; jj++){
        int nloc = (2 * jj + p) * 16 + l15;
        int n    = c * 64 + nloc;
        float pa = acc[2 * c + jj][r] * inv_l[r];
        __builtin_nontemporal_store(pa, &pA[(size_t)rl * SEQ + n]);
        float a  = arow_base[(size_t)rl * SEQ + n];
        float dd = drow_base[(size_t)rl * SEQ + n];
        float mk = sMask[n];
        float pd = (mk == 0.f) ? 0.f : __expf(-dd) * il;
        float pw = LAMBDA_A * pa + LAMBDA_D * pd + LAMBDA_J * a * ia;
        sPW[rl * 72 + nloc] = (short)f2bf(pw);
      }
    }
    __syncthreads();
#pragma unroll
    for (int ks = 0; ks < 2; ks++){
      shortx8 af = *(const shortx8*)&sPW[(mtile * 16 + l15) * 72 + ks * 32 + quad * 8];
      shortx8 b0 = *(const shortx8*)&sKV[(p * 16 + l15) * 72 + ks * 32 + quad * 8];
      acc2[0] = __builtin_amdgcn_mfma_f32_16x16x32_bf16(af, b0, acc2[0], 0, 0, 0);
      shortx8 b1 = *(const shortx8*)&sKV[((p + 2) * 16 + l15) * 72 + ks * 32 + quad * 8];
      acc2[1] = __builtin_amdgcn_mfma_f32_16x16x32_bf16(af, b1, acc2[1], 0, 0, 0);
    }
  }

  // ---- epilogue: out (B,H,S,D) ----
  float* ob = out + ((size_t)bh * SEQ + q0) * DIM;
#pragma unroll
  for (int t = 0; t < 2; t++){
    int nt = p + 2 * t;
#pragma unroll
    for (int r = 0; r < 4; r++){
      int rl = mtile * 16 + quad * 4 + r;
      __builtin_nontemporal_store(acc2[t][r], &ob[(size_t)rl * DIM + nt * 16 + l15]);
    }
  }
}

extern "C" void kernel_launch(void* const* d_in, const int* in_sizes, int n_in,
                              void* d_out, int out_size, void* d_ws, size_t ws_size,
                              hipStream_t stream){
  const float* Q    = (const float*)d_in[0];
  const float* K    = (const float*)d_in[1];
  const float* V    = (const float*)d_in[2];
  const float* mask = (const float*)d_in[3];
  const float* adj  = (const float*)d_in[4];
  const float* dist = (const float*)d_in[5];
  float* out   = (float*)d_out;
  float* pattn = out + (size_t)BATCH * HEADS * SEQ * DIM;   // 8,388,608

  attn_kernel<<<BATCH * HEADS * (SEQ / QT), 256, 0, stream>>>(Q, K, V, mask, adj, dist,
                                                              out, pattn);
}